// Round 1
// baseline (441.434 us; speedup 1.0000x reference)
//
#include <hip/hip_runtime.h>

// SpikeLatencyLIFEncoder: per-element independent LIF latency encoding.
// v <- v + 0.1*((0 - v) + I); spike once at first threshold crossing.
// Output [100, 256, 4096] f32. HBM-write-bound (~419 MB out).

#define SEQ_LEN 100

__global__ __launch_bounds__(256) void lif_latency_kernel(
    const float4* __restrict__ in, float4* __restrict__ out, int n4) {
    int i = blockIdx.x * blockDim.x + threadIdx.x;
    if (i >= n4) return;

    float4 I4 = in[i];
    float Iv[4] = {I4.x, I4.y, I4.z, I4.w};
    int ts[4];

    // Find first-spike time per component with the exact fp32 recurrence
    // (explicit _rn intrinsics to forbid FMA contraction; must match XLA ref).
    #pragma unroll
    for (int c = 0; c < 4; ++c) {
        float Ic = Iv[c];
        float v = 0.0f;
        int t = 0;
        for (; t < SEQ_LEN; ++t) {
            // v = v + 0.1f * ((0.0f - v) + I)
            float d = __fadd_rn(__fsub_rn(0.0f, v), Ic);
            v = __fadd_rn(v, __fmul_rn(0.1f, d));
            if (v > 1.0f) break;  // equivalent to (v - 1.0f) > 0.0f in fp32
        }
        ts[c] = t;  // t == SEQ_LEN means "never spikes"
    }

    // Stream the output: one coalesced float4 store per time step.
    float4* o = out + i;
    #pragma unroll 4
    for (int t = 0; t < SEQ_LEN; ++t) {
        float4 val;
        val.x = (t == ts[0]) ? 1.0f : 0.0f;
        val.y = (t == ts[1]) ? 1.0f : 0.0f;
        val.z = (t == ts[2]) ? 1.0f : 0.0f;
        val.w = (t == ts[3]) ? 1.0f : 0.0f;
        o[(size_t)t * n4] = val;
    }
}

extern "C" void kernel_launch(void* const* d_in, const int* in_sizes, int n_in,
                              void* d_out, int out_size, void* d_ws, size_t ws_size,
                              hipStream_t stream) {
    const float* in = (const float*)d_in[0];
    float* out = (float*)d_out;
    int n = in_sizes[0];          // 256*4096 = 1,048,576 (multiple of 4)
    int n4 = n / 4;
    int threads = 256;
    int blocks = (n4 + threads - 1) / threads;
    lif_latency_kernel<<<blocks, threads, 0, stream>>>(
        (const float4*)in, (float4*)out, n4);
}